// Round 11
// baseline (209.500 us; speedup 1.0000x reference)
//
#include <hip/hip_runtime.h>
#include <hip/hip_bf16.h>

typedef __bf16 bf16;
typedef float f32x4 __attribute__((ext_vector_type(4)));
typedef float f32x16 __attribute__((ext_vector_type(16)));
typedef bf16 bf16x8 __attribute__((ext_vector_type(8)));
typedef bf16 bf16x4 __attribute__((ext_vector_type(4)));
typedef unsigned int u32;
typedef unsigned int u32x4 __attribute__((ext_vector_type(4)));

#define D_MODEL 256
#define NH 8
#define HD 32
#define SEQ 2048
#define BATCH 2
// 1/sqrt(32) * log2(e): scores in log2 domain -> exp2 = single v_exp_f32
#define SC2 0.25505654344884107f

// ---------- workspace layout (bytes) ----------
#define OFF_QB   ((size_t)0)                    // 3*2*2048*256 bf16 = 6291456
#define OFF_KB   ((size_t)6291456)
#define OFF_VT   ((size_t)12582912)             // [a][b][h][hd][s] bf16
#define OFF_PO   ((size_t)18874368)             // partial O bf16 [z=9][b][s][256] = 18874368
#define OFF_WQT  ((size_t)37748736)             // 3*256*256 bf16 = 393216
#define OFF_WKT  ((size_t)38141952)
#define OFF_WVT  ((size_t)38535168)
#define OFF_WOT  ((size_t)38928384)             // 131072
#define OFF_BQS  ((size_t)39059456)             // 768 f32

// Weight prep only (transpose+bf16, Q pre-scaled by SC2), bq scale.
// blocks 0..2303: Wq/Wk/Wv, 2304..2559: Wo, 2560..2562: bq
__global__ void conv_all(const float* __restrict__ Wq, const float* __restrict__ Wk,
                         const float* __restrict__ Wv, const float* __restrict__ Wo,
                         const float* __restrict__ bq,
                         bf16* __restrict__ wqt, bf16* __restrict__ wkt,
                         bf16* __restrict__ wvt, bf16* __restrict__ wot,
                         float* __restrict__ bqs) {
    int blk = blockIdx.x;
    int tid = threadIdx.x;
    if (blk < 2304) {
        const float* W; bf16* Wt; float scale;
        if (blk < 768)       { W = Wq; Wt = wqt; scale = SC2; }
        else if (blk < 1536) { W = Wk; Wt = wkt; scale = 1.0f; blk -= 768; }
        else                 { W = Wv; Wt = wvt; scale = 1.0f; blk -= 1536; }
        int i = blk * 256 + tid;
        int a = i >> 16;
        int r = i & 65535;
        int k = r >> 8, c = r & 255;
        Wt[(a << 16) + (c << 8) + k] = (bf16)(W[i] * scale);
    } else if (blk < 2560) {
        int i = (blk - 2304) * 256 + tid;
        int k = i >> 8, c = i & 255;
        wot[(c << 8) + k] = (bf16)Wo[i];
    } else {
        int i = (blk - 2560) * 256 + tid;
        bqs[i] = bq[i] * SC2;
    }
}

// Projection GEMM: y = x[a] @ W[t][a] + bias. 64-row x 64-col tile per block.
// Reads f32 x directly, converts in-register (fused conversion).
__global__ __launch_bounds__(256) void proj_gemm(
    const float* __restrict__ x0, const float* __restrict__ x1, const float* __restrict__ x2,
    const bf16* __restrict__ wqt, const bf16* __restrict__ wkt, const bf16* __restrict__ wvt,
    const float* __restrict__ bqs, const float* __restrict__ bk, const float* __restrict__ bv,
    bf16* __restrict__ qb, bf16* __restrict__ kb, bf16* __restrict__ vt)
{
    int mt = blockIdx.x;          // 0..63
    int ta = blockIdx.y;          // 0..8
    int ch = blockIdx.z;          // 0..3 col quarter
    int t = ta / 3, a = ta % 3;
    const float* xs = (a == 0) ? x0 : (a == 1) ? x1 : x2;
    const bf16* wt = ((t == 0) ? wqt : (t == 1) ? wkt : wvt) + a * 65536;
    const float* bias = ((t == 0) ? bqs : (t == 1) ? bk : bv) + a * 256;

    int wave = threadIdx.x >> 6;
    int lane = threadIdx.x & 63;
    int lr = lane & 15;
    int lg = lane >> 4;

    int arow = mt * 64 + wave * 16 + lr;
    f32x4 acc[4];
    f32x4 zero = {0.f, 0.f, 0.f, 0.f};
    for (int n = 0; n < 4; n++) acc[n] = zero;

    for (int ks = 0; ks < 8; ks++) {
        int kbase = ks * 32 + lg * 8;
        const float* ap = xs + arow * 256 + kbase;
        float4 a0 = *reinterpret_cast<const float4*>(ap);
        float4 a1 = *reinterpret_cast<const float4*>(ap + 4);
        bf16x8 af;
        af[0] = (bf16)a0.x; af[1] = (bf16)a0.y; af[2] = (bf16)a0.z; af[3] = (bf16)a0.w;
        af[4] = (bf16)a1.x; af[5] = (bf16)a1.y; af[6] = (bf16)a1.z; af[7] = (bf16)a1.w;
        for (int n = 0; n < 4; n++) {
            int col = ch * 64 + n * 16 + lr;
            bf16x8 bfr = *reinterpret_cast<const bf16x8*>(wt + col * 256 + kbase);
            acc[n] = __builtin_amdgcn_mfma_f32_16x16x32_bf16(af, bfr, acc[n], 0, 0, 0);
        }
    }

    if (t < 2) {
        bf16* out = ((t == 0) ? qb : kb) + (size_t)a * BATCH * SEQ * 256;
        for (int n = 0; n < 4; n++) {
            int col = ch * 64 + n * 16 + lr;
            float bc = bias[col];
            int rbase = mt * 64 + wave * 16 + lg * 4;
            for (int r = 0; r < 4; r++)
                out[(size_t)(rbase + r) * 256 + col] = (bf16)(acc[n][r] + bc);
        }
    } else {
        // vt[a][b][h][hd][s]
        for (int n = 0; n < 4; n++) {
            int col = ch * 64 + n * 16 + lr;
            float bc = bias[col];
            int h = col >> 5, hd = col & 31;
            int rbase = mt * 64 + wave * 16 + lg * 4;
            int b = rbase >> 11, s = rbase & 2047;
            bf16x4 v4;
            for (int r = 0; r < 4; r++) v4[r] = (bf16)(acc[n][r] + bc);
            bf16* dst = vt + ((size_t)(((a * BATCH + b) * NH + h) * HD + hd)) * SEQ + s;
            *reinterpret_cast<bf16x4*>(dst) = v4;
        }
    }
}

// 32x32 swapped-QK^T attention for ONE (i,j) pair per block.z.
// In-register P redistribution (cvt_pk + permlane32_swap), exp2-domain softmax,
// reg-prefetch pipeline, f32 vector lsum, setprio around MFMA pairs.
// (r8 structure + setprio; NO XCD swizzle — it cost ~2% when L2-fit.)
__global__ __launch_bounds__(256) void attn(
    const bf16* __restrict__ qb, const bf16* __restrict__ kb,
    const bf16* __restrict__ vt, bf16* __restrict__ po)
{
    __shared__ __align__(16) bf16 lk[128][40];    // K tile [key][hd], 80B rows
    __shared__ __align__(16) bf16 lv[32][136];    // V^T tile [hd][key], 272B rows

    int qt = blockIdx.x;      // 0..15 (128 q rows per block)
    int bh = blockIdx.y;      // 0..15
    int z  = blockIdx.z;      // 0..8 = i*3 + j
    int i = z / 3, j = z % 3;
    int b = bh >> 3, h = bh & 7;

    int tid = threadIdx.x;
    int wave = tid >> 6, lane = tid & 63;
    int lq = lane & 31;
    int hi = lane >> 5;

    int qrow = qt * 128 + wave * 32 + lq;
    const bf16* qp = qb + ((size_t)((i * BATCH + b) * SEQ + qrow)) * 256 + h * 32 + hi * 8;
    bf16x8 qf0 = *reinterpret_cast<const bf16x8*>(qp);
    bf16x8 qf1 = *reinterpret_cast<const bf16x8*>(qp + 16);

    int krow = tid >> 1, koff = (tid & 1) * 16;
    int vrow = tid >> 3, voff = (tid & 7) * 16;

    const bf16* kg = kb + (size_t)(j * BATCH + b) * SEQ * 256 + h * 32
                        + (size_t)krow * 256 + koff;
    const bf16* vg = vt + (size_t)((j * BATCH + b) * NH + h) * HD * SEQ
                        + (size_t)vrow * SEQ + voff;

    // prefetch tile 0
    bf16x8 k0 = *reinterpret_cast<const bf16x8*>(kg);
    bf16x8 k1 = *reinterpret_cast<const bf16x8*>(kg + 8);
    bf16x8 v0 = *reinterpret_cast<const bf16x8*>(vg);
    bf16x8 v1 = *reinterpret_cast<const bf16x8*>(vg + 8);

    const f32x16 zc = {};     // loop-invariant zero accumulator (init once)
    f32x16 o = {};
    f32x16 ls = {};           // vectorized lsum accumulator

    for (int kt = 0; kt < SEQ / 128; kt++) {
        // write staged regs (compiler inserts vmcnt wait here)
        *reinterpret_cast<bf16x8*>(&lk[krow][koff]) = k0;
        *reinterpret_cast<bf16x8*>(&lk[krow][koff + 8]) = k1;
        *reinterpret_cast<bf16x8*>(&lv[vrow][voff]) = v0;
        *reinterpret_cast<bf16x8*>(&lv[vrow][voff + 8]) = v1;
        __syncthreads();

        // issue next-tile loads; consumed at next iteration's ds_write ->
        // latency hides under the compute phase below. (Tile-16 overread
        // lands in adjacent workspace regions; data discarded.)
        kg += 128 * 256;
        vg += 128;
        k0 = *reinterpret_cast<const bf16x8*>(kg);
        k1 = *reinterpret_cast<const bf16x8*>(kg + 8);
        v0 = *reinterpret_cast<const bf16x8*>(vg);
        v1 = *reinterpret_cast<const bf16x8*>(vg + 8);
        __builtin_amdgcn_sched_barrier(0);   // pin load issue before MFMA cluster

        #pragma unroll
        for (int sub = 0; sub < 4; sub++) {
            bf16x8 kf0 = *reinterpret_cast<const bf16x8*>(&lk[sub * 32 + lq][hi * 8]);
            bf16x8 kf1 = *reinterpret_cast<const bf16x8*>(&lk[sub * 32 + lq][16 + hi * 8]);
            __builtin_amdgcn_s_setprio(1);
            f32x16 st = __builtin_amdgcn_mfma_f32_32x32x16_bf16(kf0, qf0, zc, 0, 0, 0);
            st = __builtin_amdgcn_mfma_f32_32x32x16_bf16(kf1, qf1, st, 0, 0, 0);
            __builtin_amdgcn_s_setprio(0);

            // P = 2^st in place; vector lsum accumulate
            #pragma unroll
            for (int r = 0; r < 16; r++) st[r] = __builtin_amdgcn_exp2f(st[r]);
            ls += st;

            u32 w[8];
            #pragma unroll
            for (int s = 0; s < 8; s++)
                asm("v_cvt_pk_bf16_f32 %0, %1, %2" : "=v"(w[s]) : "v"(st[2 * s]), "v"(st[2 * s + 1]));
            asm("v_permlane32_swap_b32 %0, %1" : "+v"(w[0]), "+v"(w[2]));
            asm("v_permlane32_swap_b32 %0, %1" : "+v"(w[1]), "+v"(w[3]));
            asm("v_permlane32_swap_b32 %0, %1" : "+v"(w[4]), "+v"(w[6]));
            asm("v_permlane32_swap_b32 %0, %1" : "+v"(w[5]), "+v"(w[7]));

            union { u32 u[4]; bf16x8 v; } pa0, pa1;
            pa0.u[0] = w[0]; pa0.u[1] = w[1]; pa0.u[2] = w[2]; pa0.u[3] = w[3];
            pa1.u[0] = w[4]; pa1.u[1] = w[5]; pa1.u[2] = w[6]; pa1.u[3] = w[7];

            bf16x8 vf0 = *reinterpret_cast<const bf16x8*>(&lv[lq][sub * 32 + hi * 8]);
            bf16x8 vf1 = *reinterpret_cast<const bf16x8*>(&lv[lq][sub * 32 + 16 + hi * 8]);
            __builtin_amdgcn_s_setprio(1);
            o = __builtin_amdgcn_mfma_f32_32x32x16_bf16(pa0.v, vf0, o, 0, 0, 0);
            o = __builtin_amdgcn_mfma_f32_32x32x16_bf16(pa1.v, vf1, o, 0, 0, 0);
            __builtin_amdgcn_s_setprio(0);
        }
        __syncthreads();
    }

    // finish softmax: horizontal sum of ls (16 keys this hi-half), then
    // cross-half add -> full 2048-key sum for q = lane&31
    float lsum = (((ls[0] + ls[1]) + (ls[2] + ls[3])) + ((ls[4] + ls[5]) + (ls[6] + ls[7])))
               + (((ls[8] + ls[9]) + (ls[10] + ls[11])) + ((ls[12] + ls[13]) + (ls[14] + ls[15])));
    lsum += __shfl_xor(lsum, 32);
    float inv = 1.0f / lsum;                 // inv for q = lane&31

    bf16* pop = po + ((size_t)(z * BATCH + b) * SEQ) * 256 + h * 32;
    #pragma unroll
    for (int r = 0; r < 16; r++) {
        int qr = (r & 3) + 8 * (r >> 2) + 4 * hi;
        float invr = __shfl(inv, qr, 64);
        int s = qt * 128 + wave * 32 + qr;
        pop[(size_t)s * 256 + lq] = (bf16)(o[r] * invr);
    }
}

// sum of three bf16x8 vectors in f32, repacked to bf16
__device__ inline bf16x8 comb3(const bf16* p0, const bf16* p1, const bf16* p2) {
    u32x4 a = *reinterpret_cast<const u32x4*>(p0);
    u32x4 b = *reinterpret_cast<const u32x4*>(p1);
    u32x4 c = *reinterpret_cast<const u32x4*>(p2);
    union { u32 u[4]; bf16x8 v; } r;
    #pragma unroll
    for (int d = 0; d < 4; d++) {
        float ae = __uint_as_float(a[d] << 16), ao = __uint_as_float(a[d] & 0xffff0000u);
        float be = __uint_as_float(b[d] << 16), bo = __uint_as_float(b[d] & 0xffff0000u);
        float ce = __uint_as_float(c[d] << 16), co = __uint_as_float(c[d] & 0xffff0000u);
        float se = ae + be + ce, so = ao + bo + co;
        asm("v_cvt_pk_bf16_f32 %0, %1, %2" : "=v"(r.u[d]) : "v"(se), "v"(so));
    }
    return r.v;
}

// Final projection with fused j-combine: out = (sum_j po[i*3+j]) @ Wo + bo
__global__ __launch_bounds__(256) void out_gemm(
    const bf16* __restrict__ po, const bf16* __restrict__ wot,
    const float* __restrict__ bo, float* __restrict__ out)
{
    int mt = blockIdx.x;  // 0..191
    int ch = blockIdx.y;  // 0..3 col quarter
    int wave = threadIdx.x >> 6, lane = threadIdx.x & 63;
    int lr = lane & 15, lg = lane >> 4;
    int arow = mt * 64 + wave * 16 + lr;
    int i = arow >> 12, rem = arow & 4095;

    const bf16* p0 = po + ((size_t)(i * 3 + 0) * 4096 + rem) * 256;
    const bf16* p1 = po + ((size_t)(i * 3 + 1) * 4096 + rem) * 256;
    const bf16* p2 = po + ((size_t)(i * 3 + 2) * 4096 + rem) * 256;

    f32x4 acc[4];
    f32x4 zero = {0.f, 0.f, 0.f, 0.f};
    for (int n = 0; n < 4; n++) acc[n] = zero;

    for (int ks = 0; ks < 8; ks++) {
        int kbase = ks * 32 + lg * 8;
        bf16x8 af = comb3(p0 + kbase, p1 + kbase, p2 + kbase);
        for (int n = 0; n < 4; n++) {
            int col = ch * 64 + n * 16 + lr;
            bf16x8 bfr = *reinterpret_cast<const bf16x8*>(wot + col * 256 + kbase);
            acc[n] = __builtin_amdgcn_mfma_f32_16x16x32_bf16(af, bfr, acc[n], 0, 0, 0);
        }
    }
    for (int n = 0; n < 4; n++) {
        int col = ch * 64 + n * 16 + lr;
        float bc = bo[col];
        int rbase = mt * 64 + wave * 16 + lg * 4;
        for (int r = 0; r < 4; r++)
            out[(size_t)(rbase + r) * 256 + col] = acc[n][r] + bc;
    }
}

extern "C" void kernel_launch(void* const* d_in, const int* in_sizes, int n_in,
                              void* d_out, int out_size, void* d_ws, size_t ws_size,
                              hipStream_t stream) {
    const float* x0 = (const float*)d_in[0];
    const float* x1 = (const float*)d_in[1];
    const float* x2 = (const float*)d_in[2];
    const float* Wq = (const float*)d_in[3];
    const float* bq = (const float*)d_in[4];
    const float* Wk = (const float*)d_in[5];
    const float* bk = (const float*)d_in[6];
    const float* Wv = (const float*)d_in[7];
    const float* bv = (const float*)d_in[8];
    const float* Wo = (const float*)d_in[9];
    const float* bo = (const float*)d_in[10];

    char* ws = (char*)d_ws;
    bf16* qb  = (bf16*)(ws + OFF_QB);
    bf16* kbf = (bf16*)(ws + OFF_KB);
    bf16* vt  = (bf16*)(ws + OFF_VT);
    bf16* po  = (bf16*)(ws + OFF_PO);
    bf16* wqt = (bf16*)(ws + OFF_WQT);
    bf16* wkt = (bf16*)(ws + OFF_WKT);
    bf16* wvt = (bf16*)(ws + OFF_WVT);
    bf16* wot = (bf16*)(ws + OFF_WOT);
    float* bqs = (float*)(ws + OFF_BQS);

    conv_all<<<2563, 256, 0, stream>>>(Wq, Wk, Wv, Wo, bq,
                                       wqt, wkt, wvt, wot, bqs);

    proj_gemm<<<dim3(64, 9, 4), 256, 0, stream>>>(x0, x1, x2, wqt, wkt, wvt,
                                                  bqs, bk, bv, qb, kbf, vt);
    attn<<<dim3(16, 16, 9), 256, 0, stream>>>(qb, kbf, vt, po);
    out_gemm<<<dim3(192, 4), 256, 0, stream>>>(po, wot, bo, (float*)d_out);
}

// Round 12
// 202.041 us; speedup vs baseline: 1.0369x; 1.0369x over previous
//
#include <hip/hip_runtime.h>
#include <hip/hip_bf16.h>

typedef __bf16 bf16;
typedef float f32x4 __attribute__((ext_vector_type(4)));
typedef float f32x16 __attribute__((ext_vector_type(16)));
typedef bf16 bf16x8 __attribute__((ext_vector_type(8)));
typedef bf16 bf16x4 __attribute__((ext_vector_type(4)));
typedef unsigned int u32;
typedef unsigned int u32x4 __attribute__((ext_vector_type(4)));

#define D_MODEL 256
#define NH 8
#define HD 32
#define SEQ 2048
#define BATCH 2
// 1/sqrt(32) * log2(e): scores in log2 domain -> exp2 = single v_exp_f32
#define SC2 0.25505654344884107f

// ---------- workspace layout (bytes) ----------
#define OFF_QB   ((size_t)0)                    // 3*2*2048*256 bf16 = 6291456
#define OFF_KB   ((size_t)6291456)
#define OFF_VT   ((size_t)12582912)             // [a][b][h][hd][s] bf16
#define OFF_PO   ((size_t)18874368)             // partial O bf16 [z=9][b][s][256] = 18874368
#define OFF_XB   ((size_t)37748736)             // x bf16 [a][b*s][256] = 6291456
#define OFF_WQT  ((size_t)44040192)             // 3*256*256 bf16 = 393216
#define OFF_WKT  ((size_t)44433408)
#define OFF_WVT  ((size_t)44826624)
#define OFF_WOT  ((size_t)45219840)             // 131072
#define OFF_BQS  ((size_t)45350912)             // 768 f32

// All prep: weight transpose+bf16 (Q pre-scaled by SC2), bq scale, x -> bf16.
__global__ void conv_all(const float* __restrict__ Wq, const float* __restrict__ Wk,
                         const float* __restrict__ Wv, const float* __restrict__ Wo,
                         const float* __restrict__ bq,
                         const float* __restrict__ x0, const float* __restrict__ x1,
                         const float* __restrict__ x2,
                         bf16* __restrict__ wqt, bf16* __restrict__ wkt,
                         bf16* __restrict__ wvt, bf16* __restrict__ wot,
                         float* __restrict__ bqs, bf16* __restrict__ xb) {
    int blk = blockIdx.x;
    int tid = threadIdx.x;
    if (blk < 2304) {
        const float* W; bf16* Wt; float scale;
        if (blk < 768)       { W = Wq; Wt = wqt; scale = SC2; }
        else if (blk < 1536) { W = Wk; Wt = wkt; scale = 1.0f; blk -= 768; }
        else                 { W = Wv; Wt = wvt; scale = 1.0f; blk -= 1536; }
        int i = blk * 256 + tid;
        int a = i >> 16;
        int r = i & 65535;
        int k = r >> 8, c = r & 255;
        Wt[(a << 16) + (c << 8) + k] = (bf16)(W[i] * scale);
    } else if (blk < 2560) {
        int i = (blk - 2304) * 256 + tid;
        int k = i >> 8, c = i & 255;
        wot[(c << 8) + k] = (bf16)Wo[i];
    } else if (blk < 2563) {
        int i = (blk - 2560) * 256 + tid;
        bqs[i] = bq[i] * SC2;
    } else {
        int f = ((blk - 2563) * 256 + tid) * 8;     // 0 .. 3145720
        int a = f >> 20;
        int off = f & 1048575;
        const float* xs = (a == 0) ? x0 : (a == 1) ? x1 : x2;
        float4 A = *reinterpret_cast<const float4*>(xs + off);
        float4 B = *reinterpret_cast<const float4*>(xs + off + 4);
        bf16x8 v;
        v[0] = (bf16)A.x; v[1] = (bf16)A.y; v[2] = (bf16)A.z; v[3] = (bf16)A.w;
        v[4] = (bf16)B.x; v[5] = (bf16)B.y; v[6] = (bf16)B.z; v[7] = (bf16)B.w;
        *reinterpret_cast<bf16x8*>(xb + f) = v;
    }
}

// Projection GEMM: y = xb[a] @ W[t][a] + bias. 64-row x 128-col tile per block.
__global__ __launch_bounds__(256) void proj_gemm(
    const bf16* __restrict__ xb,
    const bf16* __restrict__ wqt, const bf16* __restrict__ wkt, const bf16* __restrict__ wvt,
    const float* __restrict__ bqs, const float* __restrict__ bk, const float* __restrict__ bv,
    bf16* __restrict__ qb, bf16* __restrict__ kb, bf16* __restrict__ vt)
{
    int mt = blockIdx.x;          // 0..63
    int ta = blockIdx.y;          // 0..8
    int ch = blockIdx.z;          // 0..1 col half
    int t = ta / 3, a = ta % 3;
    const bf16* xs = xb + a * 1048576;
    const bf16* wt = ((t == 0) ? wqt : (t == 1) ? wkt : wvt) + a * 65536;
    const float* bias = ((t == 0) ? bqs : (t == 1) ? bk : bv) + a * 256;

    int wave = threadIdx.x >> 6;
    int lane = threadIdx.x & 63;
    int lr = lane & 15;
    int lg = lane >> 4;

    int arow = mt * 64 + wave * 16 + lr;
    f32x4 acc[8];
    f32x4 zero = {0.f, 0.f, 0.f, 0.f};
    for (int n = 0; n < 8; n++) acc[n] = zero;

    for (int ks = 0; ks < 8; ks++) {
        int kbase = ks * 32 + lg * 8;
        bf16x8 af = *reinterpret_cast<const bf16x8*>(xs + arow * 256 + kbase);
        for (int n = 0; n < 8; n++) {
            int col = ch * 128 + n * 16 + lr;
            bf16x8 bfr = *reinterpret_cast<const bf16x8*>(wt + col * 256 + kbase);
            acc[n] = __builtin_amdgcn_mfma_f32_16x16x32_bf16(af, bfr, acc[n], 0, 0, 0);
        }
    }

    if (t < 2) {
        bf16* out = ((t == 0) ? qb : kb) + (size_t)a * BATCH * SEQ * 256;
        for (int n = 0; n < 8; n++) {
            int col = ch * 128 + n * 16 + lr;
            float bc = bias[col];
            int rbase = mt * 64 + wave * 16 + lg * 4;
            for (int r = 0; r < 4; r++)
                out[(size_t)(rbase + r) * 256 + col] = (bf16)(acc[n][r] + bc);
        }
    } else {
        // vt[a][b][h][hd][s]
        for (int n = 0; n < 8; n++) {
            int col = ch * 128 + n * 16 + lr;
            float bc = bias[col];
            int h = col >> 5, hd = col & 31;
            int rbase = mt * 64 + wave * 16 + lg * 4;
            int b = rbase >> 11, s = rbase & 2047;
            bf16x4 v4;
            for (int r = 0; r < 4; r++) v4[r] = (bf16)(acc[n][r] + bc);
            bf16* dst = vt + ((size_t)(((a * BATCH + b) * NH + h) * HD + hd)) * SEQ + s;
            *reinterpret_cast<bf16x4*>(dst) = v4;
        }
    }
}

// 32x32 swapped-QK^T attention for ONE (i,j) pair per block.z.
// In-register P redistribution (cvt_pk + permlane32_swap), exp2-domain softmax,
// hoisted zero accumulator, vectorized lsum, reg-prefetch pipeline.
// (Best-known attn: r8 verbatim — no setprio, no XCD swizzle.)
__global__ __launch_bounds__(256) void attn(
    const bf16* __restrict__ qb, const bf16* __restrict__ kb,
    const bf16* __restrict__ vt, bf16* __restrict__ po)
{
    __shared__ __align__(16) bf16 lk[128][40];    // K tile [key][hd], 80B rows
    __shared__ __align__(16) bf16 lv[32][136];    // V^T tile [hd][key], 272B rows

    int qt = blockIdx.x;      // 0..15 (128 q rows per block)
    int bh = blockIdx.y;      // 0..15
    int z  = blockIdx.z;      // 0..8 = i*3 + j
    int i = z / 3, j = z % 3;
    int b = bh >> 3, h = bh & 7;

    int tid = threadIdx.x;
    int wave = tid >> 6, lane = tid & 63;
    int lq = lane & 31;
    int hi = lane >> 5;

    int qrow = qt * 128 + wave * 32 + lq;
    const bf16* qp = qb + ((size_t)((i * BATCH + b) * SEQ + qrow)) * 256 + h * 32 + hi * 8;
    bf16x8 qf0 = *reinterpret_cast<const bf16x8*>(qp);
    bf16x8 qf1 = *reinterpret_cast<const bf16x8*>(qp + 16);

    int krow = tid >> 1, koff = (tid & 1) * 16;
    int vrow = tid >> 3, voff = (tid & 7) * 16;

    const bf16* kg = kb + (size_t)(j * BATCH + b) * SEQ * 256 + h * 32
                        + (size_t)krow * 256 + koff;
    const bf16* vg = vt + (size_t)((j * BATCH + b) * NH + h) * HD * SEQ
                        + (size_t)vrow * SEQ + voff;

    // prefetch tile 0
    bf16x8 k0 = *reinterpret_cast<const bf16x8*>(kg);
    bf16x8 k1 = *reinterpret_cast<const bf16x8*>(kg + 8);
    bf16x8 v0 = *reinterpret_cast<const bf16x8*>(vg);
    bf16x8 v1 = *reinterpret_cast<const bf16x8*>(vg + 8);

    const f32x16 zc = {};     // loop-invariant zero accumulator (init once)
    f32x16 o = {};
    f32x16 ls = {};           // vectorized lsum accumulator

    for (int kt = 0; kt < SEQ / 128; kt++) {
        // write staged regs (compiler inserts vmcnt wait here)
        *reinterpret_cast<bf16x8*>(&lk[krow][koff]) = k0;
        *reinterpret_cast<bf16x8*>(&lk[krow][koff + 8]) = k1;
        *reinterpret_cast<bf16x8*>(&lv[vrow][voff]) = v0;
        *reinterpret_cast<bf16x8*>(&lv[vrow][voff + 8]) = v1;
        __syncthreads();

        // issue next-tile loads; consumed at next iteration's ds_write ->
        // HBM latency hides under the compute phase below. (Tile-16 overread
        // lands in adjacent workspace regions; data discarded.)
        kg += 128 * 256;
        vg += 128;
        k0 = *reinterpret_cast<const bf16x8*>(kg);
        k1 = *reinterpret_cast<const bf16x8*>(kg + 8);
        v0 = *reinterpret_cast<const bf16x8*>(vg);
        v1 = *reinterpret_cast<const bf16x8*>(vg + 8);
        __builtin_amdgcn_sched_barrier(0);   // pin load issue before MFMA cluster

        #pragma unroll
        for (int sub = 0; sub < 4; sub++) {
            bf16x8 kf0 = *reinterpret_cast<const bf16x8*>(&lk[sub * 32 + lq][hi * 8]);
            bf16x8 kf1 = *reinterpret_cast<const bf16x8*>(&lk[sub * 32 + lq][16 + hi * 8]);
            f32x16 st = __builtin_amdgcn_mfma_f32_32x32x16_bf16(kf0, qf0, zc, 0, 0, 0);
            st = __builtin_amdgcn_mfma_f32_32x32x16_bf16(kf1, qf1, st, 0, 0, 0);

            // P = 2^st in place; vector lsum accumulate (v_pk_add_f32)
            #pragma unroll
            for (int r = 0; r < 16; r++) st[r] = __builtin_amdgcn_exp2f(st[r]);
            ls += st;

            u32 w[8];
            #pragma unroll
            for (int s = 0; s < 8; s++)
                asm("v_cvt_pk_bf16_f32 %0, %1, %2" : "=v"(w[s]) : "v"(st[2 * s]), "v"(st[2 * s + 1]));
            asm("v_permlane32_swap_b32 %0, %1" : "+v"(w[0]), "+v"(w[2]));
            asm("v_permlane32_swap_b32 %0, %1" : "+v"(w[1]), "+v"(w[3]));
            asm("v_permlane32_swap_b32 %0, %1" : "+v"(w[4]), "+v"(w[6]));
            asm("v_permlane32_swap_b32 %0, %1" : "+v"(w[5]), "+v"(w[7]));

            union { u32 u[4]; bf16x8 v; } pa0, pa1;
            pa0.u[0] = w[0]; pa0.u[1] = w[1]; pa0.u[2] = w[2]; pa0.u[3] = w[3];
            pa1.u[0] = w[4]; pa1.u[1] = w[5]; pa1.u[2] = w[6]; pa1.u[3] = w[7];

            bf16x8 vf0 = *reinterpret_cast<const bf16x8*>(&lv[lq][sub * 32 + hi * 8]);
            bf16x8 vf1 = *reinterpret_cast<const bf16x8*>(&lv[lq][sub * 32 + 16 + hi * 8]);
            o = __builtin_amdgcn_mfma_f32_32x32x16_bf16(pa0.v, vf0, o, 0, 0, 0);
            o = __builtin_amdgcn_mfma_f32_32x32x16_bf16(pa1.v, vf1, o, 0, 0, 0);
        }
        __syncthreads();
    }

    // finish softmax: horizontal sum of ls (16 keys this hi-half), then
    // cross-half add -> full 2048-key sum for q = lane&31
    float lsum = (((ls[0] + ls[1]) + (ls[2] + ls[3])) + ((ls[4] + ls[5]) + (ls[6] + ls[7])))
               + (((ls[8] + ls[9]) + (ls[10] + ls[11])) + ((ls[12] + ls[13]) + (ls[14] + ls[15])));
    lsum += __shfl_xor(lsum, 32);
    float inv = 1.0f / lsum;                 // inv for q = lane&31

    bf16* pop = po + ((size_t)(z * BATCH + b) * SEQ) * 256 + h * 32;
    #pragma unroll
    for (int r = 0; r < 16; r++) {
        int qr = (r & 3) + 8 * (r >> 2) + 4 * hi;
        float invr = __shfl(inv, qr, 64);
        int s = qt * 128 + wave * 32 + qr;
        pop[(size_t)s * 256 + lq] = (bf16)(o[r] * invr);
    }
}

// sum of three bf16x8 vectors in f32, repacked to bf16
__device__ inline bf16x8 comb3(const bf16* p0, const bf16* p1, const bf16* p2) {
    u32x4 a = *reinterpret_cast<const u32x4*>(p0);
    u32x4 b = *reinterpret_cast<const u32x4*>(p1);
    u32x4 c = *reinterpret_cast<const u32x4*>(p2);
    union { u32 u[4]; bf16x8 v; } r;
    #pragma unroll
    for (int d = 0; d < 4; d++) {
        float ae = __uint_as_float(a[d] << 16), ao = __uint_as_float(a[d] & 0xffff0000u);
        float be = __uint_as_float(b[d] << 16), bo = __uint_as_float(b[d] & 0xffff0000u);
        float ce = __uint_as_float(c[d] << 16), co = __uint_as_float(c[d] & 0xffff0000u);
        float se = ae + be + ce, so = ao + bo + co;
        asm("v_cvt_pk_bf16_f32 %0, %1, %2" : "=v"(r.u[d]) : "v"(se), "v"(so));
    }
    return r.v;
}

// Final projection with fused j-combine: out = (sum_j po[i*3+j]) @ Wo + bo
__global__ __launch_bounds__(256) void out_gemm(
    const bf16* __restrict__ po, const bf16* __restrict__ wot,
    const float* __restrict__ bo, float* __restrict__ out)
{
    int mt = blockIdx.x;  // 0..191
    int ch = blockIdx.y;  // 0..1 col half
    int wave = threadIdx.x >> 6, lane = threadIdx.x & 63;
    int lr = lane & 15, lg = lane >> 4;
    int arow = mt * 64 + wave * 16 + lr;
    int i = arow >> 12, rem = arow & 4095;

    const bf16* p0 = po + ((size_t)(i * 3 + 0) * 4096 + rem) * 256;
    const bf16* p1 = po + ((size_t)(i * 3 + 1) * 4096 + rem) * 256;
    const bf16* p2 = po + ((size_t)(i * 3 + 2) * 4096 + rem) * 256;

    f32x4 acc[8];
    f32x4 zero = {0.f, 0.f, 0.f, 0.f};
    for (int n = 0; n < 8; n++) acc[n] = zero;

    for (int ks = 0; ks < 8; ks++) {
        int kbase = ks * 32 + lg * 8;
        bf16x8 af = comb3(p0 + kbase, p1 + kbase, p2 + kbase);
        for (int n = 0; n < 8; n++) {
            int col = ch * 128 + n * 16 + lr;
            bf16x8 bfr = *reinterpret_cast<const bf16x8*>(wot + col * 256 + kbase);
            acc[n] = __builtin_amdgcn_mfma_f32_16x16x32_bf16(af, bfr, acc[n], 0, 0, 0);
        }
    }
    for (int n = 0; n < 8; n++) {
        int col = ch * 128 + n * 16 + lr;
        float bc = bo[col];
        int rbase = mt * 64 + wave * 16 + lg * 4;
        for (int r = 0; r < 4; r++)
            out[(size_t)(rbase + r) * 256 + col] = acc[n][r] + bc;
    }
}

extern "C" void kernel_launch(void* const* d_in, const int* in_sizes, int n_in,
                              void* d_out, int out_size, void* d_ws, size_t ws_size,
                              hipStream_t stream) {
    const float* x0 = (const float*)d_in[0];
    const float* x1 = (const float*)d_in[1];
    const float* x2 = (const float*)d_in[2];
    const float* Wq = (const float*)d_in[3];
    const float* bq = (const float*)d_in[4];
    const float* Wk = (const float*)d_in[5];
    const float* bk = (const float*)d_in[6];
    const float* Wv = (const float*)d_in[7];
    const float* bv = (const float*)d_in[8];
    const float* Wo = (const float*)d_in[9];
    const float* bo = (const float*)d_in[10];

    char* ws = (char*)d_ws;
    bf16* qb  = (bf16*)(ws + OFF_QB);
    bf16* kbf = (bf16*)(ws + OFF_KB);
    bf16* vt  = (bf16*)(ws + OFF_VT);
    bf16* po  = (bf16*)(ws + OFF_PO);
    bf16* xb  = (bf16*)(ws + OFF_XB);
    bf16* wqt = (bf16*)(ws + OFF_WQT);
    bf16* wkt = (bf16*)(ws + OFF_WKT);
    bf16* wvt = (bf16*)(ws + OFF_WVT);
    bf16* wot = (bf16*)(ws + OFF_WOT);
    float* bqs = (float*)(ws + OFF_BQS);

    conv_all<<<4099, 256, 0, stream>>>(Wq, Wk, Wv, Wo, bq, x0, x1, x2,
                                       wqt, wkt, wvt, wot, bqs, xb);

    proj_gemm<<<dim3(64, 9, 2), 256, 0, stream>>>(xb, wqt, wkt, wvt,
                                                  bqs, bk, bv, qb, kbf, vt);
    attn<<<dim3(16, 16, 9), 256, 0, stream>>>(qb, kbf, vt, po);
    out_gemm<<<dim3(192, 2), 256, 0, stream>>>(po, wot, bo, (float*)d_out);
}

// Round 13
// 199.516 us; speedup vs baseline: 1.0500x; 1.0127x over previous
//
#include <hip/hip_runtime.h>
#include <hip/hip_bf16.h>

typedef __bf16 bf16;
typedef float f32x4 __attribute__((ext_vector_type(4)));
typedef float f32x16 __attribute__((ext_vector_type(16)));
typedef bf16 bf16x8 __attribute__((ext_vector_type(8)));
typedef bf16 bf16x4 __attribute__((ext_vector_type(4)));
typedef unsigned int u32;
typedef unsigned int u32x4 __attribute__((ext_vector_type(4)));

#define D_MODEL 256
#define NH 8
#define HD 32
#define SEQ 2048
#define BATCH 2
// 1/sqrt(32) * log2(e): scores in log2 domain -> exp2 = single v_exp_f32
#define SC2 0.25505654344884107f

// ---------- workspace layout (bytes) ----------
#define OFF_QB   ((size_t)0)                    // 3*2*2048*256 bf16 = 6291456
#define OFF_KB   ((size_t)6291456)
#define OFF_VT   ((size_t)12582912)             // [a][b][h][hd][s] bf16
#define OFF_PO   ((size_t)18874368)             // partial O bf16 [z=9][b][s][256] = 18874368
#define OFF_XB   ((size_t)37748736)             // x bf16 [a][b*s][256] = 6291456
#define OFF_WQT  ((size_t)44040192)             // 3*256*256 bf16 = 393216
#define OFF_WKT  ((size_t)44433408)
#define OFF_WVT  ((size_t)44826624)
#define OFF_WOT  ((size_t)45219840)             // 131072
#define OFF_BQS  ((size_t)45350912)             // 768 f32

// All prep: weight transpose+bf16 (Q pre-scaled by SC2), bq scale, x -> bf16.
__global__ void conv_all(const float* __restrict__ Wq, const float* __restrict__ Wk,
                         const float* __restrict__ Wv, const float* __restrict__ Wo,
                         const float* __restrict__ bq,
                         const float* __restrict__ x0, const float* __restrict__ x1,
                         const float* __restrict__ x2,
                         bf16* __restrict__ wqt, bf16* __restrict__ wkt,
                         bf16* __restrict__ wvt, bf16* __restrict__ wot,
                         float* __restrict__ bqs, bf16* __restrict__ xb) {
    int blk = blockIdx.x;
    int tid = threadIdx.x;
    if (blk < 2304) {
        const float* W; bf16* Wt; float scale;
        if (blk < 768)       { W = Wq; Wt = wqt; scale = SC2; }
        else if (blk < 1536) { W = Wk; Wt = wkt; scale = 1.0f; blk -= 768; }
        else                 { W = Wv; Wt = wvt; scale = 1.0f; blk -= 1536; }
        int i = blk * 256 + tid;
        int a = i >> 16;
        int r = i & 65535;
        int k = r >> 8, c = r & 255;
        Wt[(a << 16) + (c << 8) + k] = (bf16)(W[i] * scale);
    } else if (blk < 2560) {
        int i = (blk - 2304) * 256 + tid;
        int k = i >> 8, c = i & 255;
        wot[(c << 8) + k] = (bf16)Wo[i];
    } else if (blk < 2563) {
        int i = (blk - 2560) * 256 + tid;
        bqs[i] = bq[i] * SC2;
    } else {
        int f = ((blk - 2563) * 256 + tid) * 8;     // 0 .. 3145720
        int a = f >> 20;
        int off = f & 1048575;
        const float* xs = (a == 0) ? x0 : (a == 1) ? x1 : x2;
        float4 A = *reinterpret_cast<const float4*>(xs + off);
        float4 B = *reinterpret_cast<const float4*>(xs + off + 4);
        bf16x8 v;
        v[0] = (bf16)A.x; v[1] = (bf16)A.y; v[2] = (bf16)A.z; v[3] = (bf16)A.w;
        v[4] = (bf16)B.x; v[5] = (bf16)B.y; v[6] = (bf16)B.z; v[7] = (bf16)B.w;
        *reinterpret_cast<bf16x8*>(xb + f) = v;
    }
}

// Projection GEMM: y = xb[a] @ W[t][a] + bias. 64-row x 128-col tile per block.
__global__ __launch_bounds__(256) void proj_gemm(
    const bf16* __restrict__ xb,
    const bf16* __restrict__ wqt, const bf16* __restrict__ wkt, const bf16* __restrict__ wvt,
    const float* __restrict__ bqs, const float* __restrict__ bk, const float* __restrict__ bv,
    bf16* __restrict__ qb, bf16* __restrict__ kb, bf16* __restrict__ vt)
{
    int mt = blockIdx.x;          // 0..63
    int ta = blockIdx.y;          // 0..8
    int ch = blockIdx.z;          // 0..1 col half
    int t = ta / 3, a = ta % 3;
    const bf16* xs = xb + a * 1048576;
    const bf16* wt = ((t == 0) ? wqt : (t == 1) ? wkt : wvt) + a * 65536;
    const float* bias = ((t == 0) ? bqs : (t == 1) ? bk : bv) + a * 256;

    int wave = threadIdx.x >> 6;
    int lane = threadIdx.x & 63;
    int lr = lane & 15;
    int lg = lane >> 4;

    int arow = mt * 64 + wave * 16 + lr;
    f32x4 acc[8];
    f32x4 zero = {0.f, 0.f, 0.f, 0.f};
    for (int n = 0; n < 8; n++) acc[n] = zero;

    for (int ks = 0; ks < 8; ks++) {
        int kbase = ks * 32 + lg * 8;
        bf16x8 af = *reinterpret_cast<const bf16x8*>(xs + arow * 256 + kbase);
        for (int n = 0; n < 8; n++) {
            int col = ch * 128 + n * 16 + lr;
            bf16x8 bfr = *reinterpret_cast<const bf16x8*>(wt + col * 256 + kbase);
            acc[n] = __builtin_amdgcn_mfma_f32_16x16x32_bf16(af, bfr, acc[n], 0, 0, 0);
        }
    }

    if (t < 2) {
        bf16* out = ((t == 0) ? qb : kb) + (size_t)a * BATCH * SEQ * 256;
        for (int n = 0; n < 8; n++) {
            int col = ch * 128 + n * 16 + lr;
            float bc = bias[col];
            int rbase = mt * 64 + wave * 16 + lg * 4;
            for (int r = 0; r < 4; r++)
                out[(size_t)(rbase + r) * 256 + col] = (bf16)(acc[n][r] + bc);
        }
    } else {
        // vt[a][b][h][hd][s]
        for (int n = 0; n < 8; n++) {
            int col = ch * 128 + n * 16 + lr;
            float bc = bias[col];
            int h = col >> 5, hd = col & 31;
            int rbase = mt * 64 + wave * 16 + lg * 4;
            int b = rbase >> 11, s = rbase & 2047;
            bf16x4 v4;
            for (int r = 0; r < 4; r++) v4[r] = (bf16)(acc[n][r] + bc);
            bf16* dst = vt + ((size_t)(((a * BATCH + b) * NH + h) * HD + hd)) * SEQ + s;
            *reinterpret_cast<bf16x4*>(dst) = v4;
        }
    }
}

// 32x32 swapped-QK^T attention, ONE (i,j) pair per block.z, TWO independent
// 32-row q-blocks per wave (256 q rows / block): stB's QK MFMAs overlap stA's
// exp/cvt VALU chain (cross-pipe ILP), and K/V fragment ds_reads + staging are
// amortized over 2x scores. exp2-domain softmax, in-register P redistribution.
__global__ __launch_bounds__(256) void attn(
    const bf16* __restrict__ qb, const bf16* __restrict__ kb,
    const bf16* __restrict__ vt, bf16* __restrict__ po)
{
    __shared__ __align__(16) bf16 lk[128][40];    // K tile [key][hd], 80B rows
    __shared__ __align__(16) bf16 lv[32][136];    // V^T tile [hd][key], 272B rows

    int qt = blockIdx.x;      // 0..7 (256 q rows per block)
    int bh = blockIdx.y;      // 0..15
    int z  = blockIdx.z;      // 0..8 = i*3 + j
    int i = z / 3, j = z % 3;
    int b = bh >> 3, h = bh & 7;

    int tid = threadIdx.x;
    int wave = tid >> 6, lane = tid & 63;
    int lq = lane & 31;
    int hi = lane >> 5;

    int qrowA = qt * 256 + wave * 32 + lq;        // q-block A; B = A + 128
    const bf16* qpA = qb + ((size_t)((i * BATCH + b) * SEQ + qrowA)) * 256 + h * 32 + hi * 8;
    const bf16* qpB = qpA + 128 * 256;
    bf16x8 qf0a = *reinterpret_cast<const bf16x8*>(qpA);
    bf16x8 qf1a = *reinterpret_cast<const bf16x8*>(qpA + 16);
    bf16x8 qf0b = *reinterpret_cast<const bf16x8*>(qpB);
    bf16x8 qf1b = *reinterpret_cast<const bf16x8*>(qpB + 16);

    int krow = tid >> 1, koff = (tid & 1) * 16;
    int vrow = tid >> 3, voff = (tid & 7) * 16;

    const bf16* kg = kb + (size_t)(j * BATCH + b) * SEQ * 256 + h * 32
                        + (size_t)krow * 256 + koff;
    const bf16* vg = vt + (size_t)((j * BATCH + b) * NH + h) * HD * SEQ
                        + (size_t)vrow * SEQ + voff;

    // prefetch tile 0
    bf16x8 k0 = *reinterpret_cast<const bf16x8*>(kg);
    bf16x8 k1 = *reinterpret_cast<const bf16x8*>(kg + 8);
    bf16x8 v0 = *reinterpret_cast<const bf16x8*>(vg);
    bf16x8 v1 = *reinterpret_cast<const bf16x8*>(vg + 8);

    const f32x16 zc = {};     // loop-invariant zero accumulator (init once)
    f32x16 oA = {}, oB = {};
    f32x16 lsA = {}, lsB = {};

    for (int kt = 0; kt < SEQ / 128; kt++) {
        // write staged regs (compiler inserts vmcnt wait here)
        *reinterpret_cast<bf16x8*>(&lk[krow][koff]) = k0;
        *reinterpret_cast<bf16x8*>(&lk[krow][koff + 8]) = k1;
        *reinterpret_cast<bf16x8*>(&lv[vrow][voff]) = v0;
        *reinterpret_cast<bf16x8*>(&lv[vrow][voff + 8]) = v1;
        __syncthreads();

        // issue next-tile loads; consumed at next iteration's ds_write ->
        // HBM latency hides under the compute phase below. (Tile-16 overread
        // lands in adjacent workspace regions; data discarded.)
        kg += 128 * 256;
        vg += 128;
        k0 = *reinterpret_cast<const bf16x8*>(kg);
        k1 = *reinterpret_cast<const bf16x8*>(kg + 8);
        v0 = *reinterpret_cast<const bf16x8*>(vg);
        v1 = *reinterpret_cast<const bf16x8*>(vg + 8);
        __builtin_amdgcn_sched_barrier(0);   // pin load issue before MFMA cluster

        #pragma unroll
        for (int sub = 0; sub < 4; sub++) {
            bf16x8 kf0 = *reinterpret_cast<const bf16x8*>(&lk[sub * 32 + lq][hi * 8]);
            bf16x8 kf1 = *reinterpret_cast<const bf16x8*>(&lk[sub * 32 + lq][16 + hi * 8]);
            // two independent QK^T chains -> MFMA pipe stays busy while the
            // other block's exp/cvt chain runs on VALU/trans
            f32x16 stA = __builtin_amdgcn_mfma_f32_32x32x16_bf16(kf0, qf0a, zc, 0, 0, 0);
            stA = __builtin_amdgcn_mfma_f32_32x32x16_bf16(kf1, qf1a, stA, 0, 0, 0);
            f32x16 stB = __builtin_amdgcn_mfma_f32_32x32x16_bf16(kf0, qf0b, zc, 0, 0, 0);
            stB = __builtin_amdgcn_mfma_f32_32x32x16_bf16(kf1, qf1b, stB, 0, 0, 0);

            #pragma unroll
            for (int r = 0; r < 16; r++) stA[r] = __builtin_amdgcn_exp2f(stA[r]);
            lsA += stA;
            u32 wA[8];
            #pragma unroll
            for (int s = 0; s < 8; s++)
                asm("v_cvt_pk_bf16_f32 %0, %1, %2" : "=v"(wA[s]) : "v"(stA[2 * s]), "v"(stA[2 * s + 1]));
            asm("v_permlane32_swap_b32 %0, %1" : "+v"(wA[0]), "+v"(wA[2]));
            asm("v_permlane32_swap_b32 %0, %1" : "+v"(wA[1]), "+v"(wA[3]));
            asm("v_permlane32_swap_b32 %0, %1" : "+v"(wA[4]), "+v"(wA[6]));
            asm("v_permlane32_swap_b32 %0, %1" : "+v"(wA[5]), "+v"(wA[7]));
            union { u32 u[4]; bf16x8 v; } paA0, paA1;
            paA0.u[0] = wA[0]; paA0.u[1] = wA[1]; paA0.u[2] = wA[2]; paA0.u[3] = wA[3];
            paA1.u[0] = wA[4]; paA1.u[1] = wA[5]; paA1.u[2] = wA[6]; paA1.u[3] = wA[7];

            #pragma unroll
            for (int r = 0; r < 16; r++) stB[r] = __builtin_amdgcn_exp2f(stB[r]);
            lsB += stB;
            u32 wB[8];
            #pragma unroll
            for (int s = 0; s < 8; s++)
                asm("v_cvt_pk_bf16_f32 %0, %1, %2" : "=v"(wB[s]) : "v"(stB[2 * s]), "v"(stB[2 * s + 1]));
            asm("v_permlane32_swap_b32 %0, %1" : "+v"(wB[0]), "+v"(wB[2]));
            asm("v_permlane32_swap_b32 %0, %1" : "+v"(wB[1]), "+v"(wB[3]));
            asm("v_permlane32_swap_b32 %0, %1" : "+v"(wB[4]), "+v"(wB[6]));
            asm("v_permlane32_swap_b32 %0, %1" : "+v"(wB[5]), "+v"(wB[7]));
            union { u32 u[4]; bf16x8 v; } paB0, paB1;
            paB0.u[0] = wB[0]; paB0.u[1] = wB[1]; paB0.u[2] = wB[2]; paB0.u[3] = wB[3];
            paB1.u[0] = wB[4]; paB1.u[1] = wB[5]; paB1.u[2] = wB[6]; paB1.u[3] = wB[7];

            bf16x8 vf0 = *reinterpret_cast<const bf16x8*>(&lv[lq][sub * 32 + hi * 8]);
            bf16x8 vf1 = *reinterpret_cast<const bf16x8*>(&lv[lq][sub * 32 + 16 + hi * 8]);
            oA = __builtin_amdgcn_mfma_f32_32x32x16_bf16(paA0.v, vf0, oA, 0, 0, 0);
            oA = __builtin_amdgcn_mfma_f32_32x32x16_bf16(paA1.v, vf1, oA, 0, 0, 0);
            oB = __builtin_amdgcn_mfma_f32_32x32x16_bf16(paB0.v, vf0, oB, 0, 0, 0);
            oB = __builtin_amdgcn_mfma_f32_32x32x16_bf16(paB1.v, vf1, oB, 0, 0, 0);
        }
        __syncthreads();
    }

    // finish softmax per q-block: horizontal sum, cross-half add, normalize
    float lsumA = (((lsA[0] + lsA[1]) + (lsA[2] + lsA[3])) + ((lsA[4] + lsA[5]) + (lsA[6] + lsA[7])))
                + (((lsA[8] + lsA[9]) + (lsA[10] + lsA[11])) + ((lsA[12] + lsA[13]) + (lsA[14] + lsA[15])));
    lsumA += __shfl_xor(lsumA, 32);
    float invA = 1.0f / lsumA;
    float lsumB = (((lsB[0] + lsB[1]) + (lsB[2] + lsB[3])) + ((lsB[4] + lsB[5]) + (lsB[6] + lsB[7])))
                + (((lsB[8] + lsB[9]) + (lsB[10] + lsB[11])) + ((lsB[12] + lsB[13]) + (lsB[14] + lsB[15])));
    lsumB += __shfl_xor(lsumB, 32);
    float invB = 1.0f / lsumB;

    bf16* pop = po + ((size_t)(z * BATCH + b) * SEQ) * 256 + h * 32;
    #pragma unroll
    for (int r = 0; r < 16; r++) {
        int qr = (r & 3) + 8 * (r >> 2) + 4 * hi;
        int sA = qt * 256 + wave * 32 + qr;
        float invrA = __shfl(invA, qr, 64);
        pop[(size_t)sA * 256 + lq] = (bf16)(oA[r] * invrA);
        float invrB = __shfl(invB, qr, 64);
        pop[(size_t)(sA + 128) * 256 + lq] = (bf16)(oB[r] * invrB);
    }
}

// sum of three bf16x8 vectors in f32, repacked to bf16
__device__ inline bf16x8 comb3(const bf16* p0, const bf16* p1, const bf16* p2) {
    u32x4 a = *reinterpret_cast<const u32x4*>(p0);
    u32x4 b = *reinterpret_cast<const u32x4*>(p1);
    u32x4 c = *reinterpret_cast<const u32x4*>(p2);
    union { u32 u[4]; bf16x8 v; } r;
    #pragma unroll
    for (int d = 0; d < 4; d++) {
        float ae = __uint_as_float(a[d] << 16), ao = __uint_as_float(a[d] & 0xffff0000u);
        float be = __uint_as_float(b[d] << 16), bo = __uint_as_float(b[d] & 0xffff0000u);
        float ce = __uint_as_float(c[d] << 16), co = __uint_as_float(c[d] & 0xffff0000u);
        float se = ae + be + ce, so = ao + bo + co;
        asm("v_cvt_pk_bf16_f32 %0, %1, %2" : "=v"(r.u[d]) : "v"(se), "v"(so));
    }
    return r.v;
}

// Final projection with fused j-combine: out = (sum_j po[i*3+j]) @ Wo + bo
__global__ __launch_bounds__(256) void out_gemm(
    const bf16* __restrict__ po, const bf16* __restrict__ wot,
    const float* __restrict__ bo, float* __restrict__ out)
{
    int mt = blockIdx.x;  // 0..191
    int ch = blockIdx.y;  // 0..1 col half
    int wave = threadIdx.x >> 6, lane = threadIdx.x & 63;
    int lr = lane & 15, lg = lane >> 4;
    int arow = mt * 64 + wave * 16 + lr;
    int i = arow >> 12, rem = arow & 4095;

    const bf16* p0 = po + ((size_t)(i * 3 + 0) * 4096 + rem) * 256;
    const bf16* p1 = po + ((size_t)(i * 3 + 1) * 4096 + rem) * 256;
    const bf16* p2 = po + ((size_t)(i * 3 + 2) * 4096 + rem) * 256;

    f32x4 acc[8];
    f32x4 zero = {0.f, 0.f, 0.f, 0.f};
    for (int n = 0; n < 8; n++) acc[n] = zero;

    for (int ks = 0; ks < 8; ks++) {
        int kbase = ks * 32 + lg * 8;
        bf16x8 af = comb3(p0 + kbase, p1 + kbase, p2 + kbase);
        for (int n = 0; n < 8; n++) {
            int col = ch * 128 + n * 16 + lr;
            bf16x8 bfr = *reinterpret_cast<const bf16x8*>(wot + col * 256 + kbase);
            acc[n] = __builtin_amdgcn_mfma_f32_16x16x32_bf16(af, bfr, acc[n], 0, 0, 0);
        }
    }
    for (int n = 0; n < 8; n++) {
        int col = ch * 128 + n * 16 + lr;
        float bc = bo[col];
        int rbase = mt * 64 + wave * 16 + lg * 4;
        for (int r = 0; r < 4; r++)
            out[(size_t)(rbase + r) * 256 + col] = acc[n][r] + bc;
    }
}

extern "C" void kernel_launch(void* const* d_in, const int* in_sizes, int n_in,
                              void* d_out, int out_size, void* d_ws, size_t ws_size,
                              hipStream_t stream) {
    const float* x0 = (const float*)d_in[0];
    const float* x1 = (const float*)d_in[1];
    const float* x2 = (const float*)d_in[2];
    const float* Wq = (const float*)d_in[3];
    const float* bq = (const float*)d_in[4];
    const float* Wk = (const float*)d_in[5];
    const float* bk = (const float*)d_in[6];
    const float* Wv = (const float*)d_in[7];
    const float* bv = (const float*)d_in[8];
    const float* Wo = (const float*)d_in[9];
    const float* bo = (const float*)d_in[10];

    char* ws = (char*)d_ws;
    bf16* qb  = (bf16*)(ws + OFF_QB);
    bf16* kbf = (bf16*)(ws + OFF_KB);
    bf16* vt  = (bf16*)(ws + OFF_VT);
    bf16* po  = (bf16*)(ws + OFF_PO);
    bf16* xb  = (bf16*)(ws + OFF_XB);
    bf16* wqt = (bf16*)(ws + OFF_WQT);
    bf16* wkt = (bf16*)(ws + OFF_WKT);
    bf16* wvt = (bf16*)(ws + OFF_WVT);
    bf16* wot = (bf16*)(ws + OFF_WOT);
    float* bqs = (float*)(ws + OFF_BQS);

    conv_all<<<4099, 256, 0, stream>>>(Wq, Wk, Wv, Wo, bq, x0, x1, x2,
                                       wqt, wkt, wvt, wot, bqs, xb);

    proj_gemm<<<dim3(64, 9, 2), 256, 0, stream>>>(xb, wqt, wkt, wvt,
                                                  bqs, bk, bv, qb, kbf, vt);
    attn<<<dim3(8, 16, 9), 256, 0, stream>>>(qb, kbf, vt, po);
    out_gemm<<<dim3(192, 2), 256, 0, stream>>>(po, wot, bo, (float*)d_out);
}